// Round 2
// baseline (158.123 us; speedup 1.0000x reference)
//
#include <hip/hip_runtime.h>

// ROIAlign: features (B=4, C=64, H=38, W=38) fp32, rois (B=4, 2904, 4) fp32
// out: (N=11616, C=64, 7, 7) fp32
// R6: phase-overlap attack. R4/R5 showed instr count, VALU count, and gather
// line volume are all NOT the bottleneck (each halved with ~no effect), so the
// remaining invariant is the barrier-serialized per-ROI phase structure.
// New shape: 4 ROIs per block, 512 threads, ping-pong LDS result tiles,
// pipeline {gather(r+1) || store(r)} so store bursts overlap gather latency
// inside the block instead of relying on inter-block stagger.
#define OUTSZ 7
#define PP    (OUTSZ * OUTSZ)   // 49 sample positions per ROI
#define NCH   64
#define FH    38
#define FW    38
#define NB    2904
#define HWSZ  (FH * FW)         // 1444
#define CHW   (NCH * HWSZ)      // 92416 per batch
#define ROI_ELEMS (NCH * PP)    // 3136 floats per ROI
#define RPB   4                 // ROIs per block (2904 % 4 == 0 -> blocks never straddle batches)

typedef __attribute__((ext_vector_type(4))) _Float16 half4;
typedef __attribute__((ext_vector_type(8))) _Float16 half8;
typedef __attribute__((ext_vector_type(4))) float    float4v;

// --- Kernel A: CHW fp32 -> HWC fp16 transpose via LDS tile (32 pos x 64 ch) ---
__global__ __launch_bounds__(256) void transpose_kernel(
    const float* __restrict__ feat,   // (4,64,38,38) fp32
    _Float16* __restrict__ fhwc)      // (4,38,38,64) fp16
{
    __shared__ float s[64][33];
    const int b   = blockIdx.y;
    const int yx0 = blockIdx.x * 32;
    const int tid  = threadIdx.x;
    const int lane = tid & 31;
    const int grp  = tid >> 5;        // 0..7

    const int yx = yx0 + lane;
    if (yx < HWSZ) {
        #pragma unroll
        for (int i = 0; i < 8; ++i) {
            const int c = grp * 8 + i;
            s[c][lane] = feat[b * CHW + c * HWSZ + yx];   // coalesced along yx
        }
    }
    __syncthreads();
    #pragma unroll
    for (int it = 0; it < 2; ++it) {
        const int item = it * 256 + tid;       // 0..511
        const int q    = item & 15;            // channel quad 0..15
        const int yxl  = item >> 4;            // 0..31
        const int yxg  = yx0 + yxl;
        if (yxg < HWSZ) {
            half4 v;
            v[0] = (_Float16)s[q * 4 + 0][yxl];
            v[1] = (_Float16)s[q * 4 + 1][yxl];
            v[2] = (_Float16)s[q * 4 + 2][yxl];
            v[3] = (_Float16)s[q * 4 + 3][yxl];
            *reinterpret_cast<half4*>(fhwc + b * CHW + yxg * NCH + q * 4) = v;
        }
    }
}

// --- Kernel B: one block (512 thr = 8 waves) per 4 ROIs, pipelined ---
__global__ __launch_bounds__(512, 8) void roi_align_kernel(
    const _Float16* __restrict__ fhwc,
    const float* __restrict__ rois,
    float* __restrict__ out)
{
    __shared__ float s_w[RPB][PP][4];
    __shared__ int   s_off[RPB][PP][4];     // element offsets into batch-HWC plane
    __shared__ float s_t[2][ROI_ELEMS];     // ping-pong result tiles, e = c*49 + p

    const int n0  = blockIdx.x * RPB;       // first roi of this block
    const int b   = n0 / NB;                // uniform: blocks never straddle batches
    const int tid = threadIdx.x;
    const _Float16* __restrict__ fb = fhwc + (size_t)b * CHW;

    // ---- Setup: weights/offsets for all 4 ROIs (784 items over 512 threads) ----
    #pragma unroll
    for (int it = 0; it < 2; ++it) {
        const int item = it * 512 + tid;
        if (item < RPB * PP * 4) {
            const int r   = item / (PP * 4);      // 0..3 (magic-mul)
            const int rem = item - r * (PP * 4);
            const int p   = rem >> 2;             // 0..48
            const int k   = rem & 3;              // corner
            const int n   = n0 + r;
            const float4v rr = *reinterpret_cast<const float4v*>(rois + n * 4);
            const float w = fmaxf(rr[2] - rr[0], 1.0f);
            const float h = fmaxf(rr[3] - rr[1], 1.0f);
            const int i = p / OUTSZ;              // row -> y (magic-mul)
            const int j = p - i * OUTSZ;          // col -> x
            const float x = rr[0] + ((float)j * (1.0f / 6.0f)) * w;
            const float y = rr[1] + ((float)i * (1.0f / 6.0f)) * h;
            const float x0f = floorf(x);
            const float y0f = floorf(y);
            const float fx = x - x0f;
            const float fy = y - y0f;
            const int dx = k & 1;
            const int dy = k >> 1;
            const float wx = dx ? fx : 1.0f - fx;
            const float wy = dy ? fy : 1.0f - fy;
            const int xc = (int)x0f + dx;
            const int yc = (int)y0f + dy;
            const bool valid = (xc >= 0) && (xc <= FW - 1) && (yc >= 0) && (yc <= FH - 1);
            const int xi = min(max(xc, 0), FW - 1);
            const int yi = min(max(yc, 0), FH - 1);
            s_w[r][p][k]   = valid ? wx * wy : 0.0f;
            s_off[r][p][k] = (yi * FW + xi) * NCH;
        }
    }

    // gather: 8 lanes per point (each owns 8 channels), all 49 points in one pass.
    // LDS write bank = (8*sub + 17*c + pg) mod 32 -> exactly 2-way (free).
    auto do_gather = [&](int r, int buf) {
        const int sub = tid & 7;            // channel octet 0..7
        const int pg  = tid >> 3;           // point 0..63 (active < 49)
        if (pg < PP) {
            const float w0 = s_w[r][pg][0], w1 = s_w[r][pg][1];
            const float w2 = s_w[r][pg][2], w3 = s_w[r][pg][3];
            const int c0 = sub * 8;
            const half8 v0 = *reinterpret_cast<const half8*>(fb + s_off[r][pg][0] + c0);
            const half8 v1 = *reinterpret_cast<const half8*>(fb + s_off[r][pg][1] + c0);
            const half8 v2 = *reinterpret_cast<const half8*>(fb + s_off[r][pg][2] + c0);
            const half8 v3 = *reinterpret_cast<const half8*>(fb + s_off[r][pg][3] + c0);
            #pragma unroll
            for (int c = 0; c < 8; ++c) {
                s_t[buf][(c0 + c) * PP + pg] =
                    (float)v0[c] * w0 + (float)v1[c] * w1 +
                    (float)v2[c] * w2 + (float)v3[c] * w3;
            }
        }
    };

    // store: straight flat copy of one tile, float4 nontemporal (784 vec4s).
    auto do_store = [&](int r, int buf) {
        float* __restrict__ ob = out + (size_t)(n0 + r) * ROI_ELEMS;
        #pragma unroll
        for (int it = 0; it < 2; ++it) {
            const int idx = it * 512 + tid;
            if (idx < ROI_ELEMS / 4) {
                const float4v t = *reinterpret_cast<const float4v*>(&s_t[buf][idx * 4]);
                __builtin_nontemporal_store(t, reinterpret_cast<float4v*>(ob + idx * 4));
            }
        }
    };

    __syncthreads();
    do_gather(0, 0);
    __syncthreads();
    do_gather(1, 1);   // issue next-ROI gathers first...
    do_store(0, 0);    // ...store of previous tile overlaps their latency
    __syncthreads();
    do_gather(2, 0);
    do_store(1, 1);
    __syncthreads();
    do_gather(3, 1);
    do_store(2, 0);
    __syncthreads();
    do_store(3, 1);
}

extern "C" void kernel_launch(void* const* d_in, const int* in_sizes, int n_in,
                              void* d_out, int out_size, void* d_ws, size_t ws_size,
                              hipStream_t stream) {
    const float* feat = (const float*)d_in[0];   // 4*64*38*38
    const float* rois = (const float*)d_in[1];   // 4*2904*4
    float* out  = (float*)d_out;                 // 11616*64*7*7
    _Float16* fhwc = (_Float16*)d_ws;            // 4*38*38*64 fp16 = 739 KB scratch

    dim3 tg((HWSZ + 31) / 32, 4);
    transpose_kernel<<<tg, 256, 0, stream>>>(feat, fhwc);
    roi_align_kernel<<<(4 * NB) / RPB, 512, 0, stream>>>(fhwc, rois, out);
}